// Round 8
// baseline (325.999 us; speedup 1.0000x reference)
//
#include <hip/hip_runtime.h>
#include <cmath>

#define B_ 2
#define S_ 2048
#define D_ 1024
#define H_ 16
#define HD_ 64
#define M_ 4096   // B*S

typedef __attribute__((ext_vector_type(8))) short short8;
typedef __attribute__((ext_vector_type(4))) short short4v;
typedef __attribute__((ext_vector_type(4))) float f32x4;

// round-to-nearest-even f32 -> bf16 (values finite here)
__device__ __forceinline__ short f2bf(float x) {
    unsigned u = __builtin_bit_cast(unsigned, x);
    u += 0x7fffu + ((u >> 16) & 1u);
    return (short)(u >> 16);
}

__device__ __forceinline__ void gload_lds16(const short* g, short* l) {
    __builtin_amdgcn_global_load_lds(
        (const __attribute__((address_space(1))) unsigned int*)g,
        (__attribute__((address_space(3))) unsigned int*)l, 16, 0, 0);
}

// ---------------------------------------------------------------------------
// cast fp32 inputs to bf16
__global__ __launch_bounds__(256) void cast_all_kernel(
    const float* __restrict__ x,  const float* __restrict__ Wq,
    const float* __restrict__ Wk, const float* __restrict__ Wv,
    const float* __restrict__ Wo,
    short* __restrict__ xb, short* __restrict__ Wqkvb, short* __restrict__ Wob)
{
    const size_t i = (size_t)blockIdx.x * 256 + threadIdx.x;  // float4 index
    const float* src; short* dst; size_t off;
    if (i < 1048576)      { src = x;  dst = xb;              off = i; }
    else if (i < 1310720) { src = Wq; dst = Wqkvb;           off = i - 1048576; }
    else if (i < 1572864) { src = Wk; dst = Wqkvb + 1048576; off = i - 1310720; }
    else if (i < 1835008) { src = Wv; dst = Wqkvb + 2097152; off = i - 1572864; }
    else                  { src = Wo; dst = Wob;             off = i - 1835008; }
    float4 v = ((const float4*)src)[off];
    short4v o = { f2bf(v.x), f2bf(v.y), f2bf(v.z), f2bf(v.w) };
    ((short4v*)dst)[off] = o;
}

// ---------------------------------------------------------------------------
// m97-style MFMA GEMM (unchanged from R7): C = A @ W^T (+bias).
template<int MODE, int TM, int TN>
__global__ __launch_bounds__(256) void gemm_tile(
    const short* __restrict__ A, const short* __restrict__ Bw,
    const float* __restrict__ b0p, const float* __restrict__ b1p, const float* __restrict__ b2p,
    const float* __restrict__ freqs,
    void* __restrict__ out0, void* __restrict__ out1, void* __restrict__ out2)
{
    constexpr int RT = TM / 32, CT = TN / 32;   // per-wave mfma tiles
    __shared__ __align__(16) short As[TM*32];
    __shared__ __align__(16) short Bs[TN*32];
    const int t = threadIdx.x;
    const int w = t >> 6;
    const int lane = t & 63;
    const int qd = lane >> 4, l = lane & 15;
    const int n0 = blockIdx.x * TN, m0 = blockIdx.y * TM;
    const int wr = (w >> 1) * (TM/2), wc = (w & 1) * (TN/2);
    const int srow = lane >> 2;
    const int scol = (lane & 3) * 8;

    f32x4 acc[RT][CT] = {};

    for (int k0 = 0; k0 < 1024; k0 += 32) {
        __syncthreads();
        #pragma unroll
        for (int j = 0; j < TM/64; ++j) {
            const int rr = (j*4 + w) * 16;
            gload_lds16(A + (size_t)(m0 + rr + srow)*1024 + k0 + scol, &As[rr*32]);
        }
        #pragma unroll
        for (int j = 0; j < TN/64; ++j) {
            const int rr = (j*4 + w) * 16;
            gload_lds16(Bw + (size_t)(n0 + rr + srow)*1024 + k0 + scol, &Bs[rr*32]);
        }
        __syncthreads();
        short8 af[RT], bf[CT];
        #pragma unroll
        for (int rt = 0; rt < RT; ++rt)
            af[rt] = *(const short8*)&As[(wr + rt*16 + l)*32 + qd*8];
        #pragma unroll
        for (int ct = 0; ct < CT; ++ct)
            bf[ct] = *(const short8*)&Bs[(wc + ct*16 + l)*32 + qd*8];
        #pragma unroll
        for (int rt = 0; rt < RT; ++rt)
            #pragma unroll
            for (int ct = 0; ct < CT; ++ct)
                acc[rt][ct] = __builtin_amdgcn_mfma_f32_16x16x32_bf16(af[rt], bf[ct], acc[rt][ct], 0, 0, 0);
    }

    if (MODE == 0) {
        float* out = (float*)out0;
        #pragma unroll
        for (int rt = 0; rt < RT; ++rt)
            #pragma unroll
            for (int ct = 0; ct < CT; ++ct) {
                const int n = n0 + wc + ct*16 + l;
                const float bias = b0p[n];
                #pragma unroll
                for (int r = 0; r < 4; ++r) {
                    const int m = m0 + wr + rt*16 + qd*4 + r;
                    out[(size_t)m*1024 + n] = acc[rt][ct][r] + bias;
                }
            }
    } else {
        const int sel = n0 >> 10;          // 0=q 1=k 2=v (uniform per block)
        const int nb = n0 & 1023;
        const float* bias = (sel == 0) ? b0p : (sel == 1) ? b1p : b2p;
        if (sel < 2) {
            short* outg = (short*)((sel == 0) ? out0 : out1);
            #pragma unroll
            for (int rt = 0; rt < RT; ++rt)
                #pragma unroll
                for (int ct = 0; ct < CT; ++ct) {
                    const int d = nb + wc + ct*16 + l;
                    const float bsv = bias[d];
                    const int h = d >> 6, hd = d & 63;
                    #pragma unroll
                    for (int r = 0; r < 4; ++r) {
                        const int m = m0 + wr + rt*16 + qd*4 + r;
                        const int bb = m >> 11, s = m & 2047;
                        float val = acc[rt][ct][r] + bsv;
                        float pv = __shfl_xor(val, 1);
                        const float* f = freqs + (size_t)s*128 + (size_t)(hd >> 1)*4;
                        float o = (d & 1) ? (f[2]*pv + f[3]*val) : (f[0]*val + f[1]*pv);
                        outg[((size_t)(bb*16 + h)*2048 + s)*64 + hd] = f2bf(o);
                    }
                }
        } else {
            short* outv = (short*)out2;
            #pragma unroll
            for (int rt = 0; rt < RT; ++rt)
                #pragma unroll
                for (int ct = 0; ct < CT; ++ct) {
                    const int d = nb + wc + ct*16 + l;
                    const float bsv = bias[d];
                    const int h = d >> 6, hd = d & 63;
                    const int m0r = m0 + wr + rt*16 + qd*4;
                    const int bb = m0r >> 11, s0 = m0r & 2047;
                    short4v pk;
                    #pragma unroll
                    for (int r = 0; r < 4; ++r) pk[r] = f2bf(acc[rt][ct][r] + bsv);
                    *(short4v*)&outv[((size_t)(bb*16 + h)*64 + hd)*2048 + s0] = pk;  // v^T
                }
        }
    }
}

// ---------------------------------------------------------------------------
// BARRIER-FREE MFMA flash attention. Block = 128 queries of one (b,h);
// 4 waves x 32 queries, fully independent (zero __syncthreads).
// K fragments for S^T = mfma(K,Q) are loaded DIRECT global->VGPR: lane l reads
// kg[(key=ct*16+l)*64 + qd*8 ..+8] — contiguous 16 B, L1/L2-served (tile is
// hot across waves/blocks). Same for V^T fragments from vtg. Only P needs an
// LDS round-trip (MFMA C->A layout transform), and P is wave-private: each
// wave owns a 32x136 strip; in-wave lgkmcnt ordering suffices, no barrier.
__global__ __launch_bounds__(256) void attn_mfma(
    const short* __restrict__ qg, const short* __restrict__ kg,
    const short* __restrict__ vtg, short* __restrict__ og)
{
    __shared__ __align__(16) short Ps[4][32*136];   // per-wave P strips, 34.8 KB

    const int t = threadIdx.x;
    const int w = t >> 6;
    const int lane = t & 63;
    const int qd = lane >> 4, l = lane & 15;
    const int q0 = blockIdx.x * 128;
    const int bh = blockIdx.y;
    short* myP = &Ps[w][0];

    // Q fragments pinned in registers (wave w: queries q0+w*32 .. +32)
    short8 qf[2][2];
    const short* qb = qg + ((size_t)bh*2048 + q0 + w*32)*64;
    #pragma unroll
    for (int rt = 0; rt < 2; ++rt)
        #pragma unroll
        for (int kf = 0; kf < 2; ++kf)
            qf[rt][kf] = *(const short8*)&qb[(rt*16 + l)*64 + kf*32 + qd*8];

    f32x4 oacc[2][4] = {};
    float lsum[2] = {};

    const short* kbase = kg  + (size_t)bh*2048*64;
    const short* vbase = vtg + (size_t)bh*64*2048;
    const float SC = 0.125f * 1.44269504088896340736f;  // 1/8 * log2(e)

    for (int kt = 0; kt < 16; ++kt) {
        const short* kt_p = kbase + (size_t)kt*128*64;

        // S^T = mfma(K, Q): m = key (ct*16+qd*4+r), n = query (rt*16+l)
        f32x4 sacc[2][8] = {};
        #pragma unroll
        for (int ct = 0; ct < 8; ++ct) {
            short8 ka = *(const short8*)(kt_p + (size_t)(ct*16 + l)*64 + qd*8);
            short8 kb = *(const short8*)(kt_p + (size_t)(ct*16 + l)*64 + 32 + qd*8);
            #pragma unroll
            for (int rt = 0; rt < 2; ++rt) {
                sacc[rt][ct] = __builtin_amdgcn_mfma_f32_16x16x32_bf16(ka, qf[rt][0], sacc[rt][ct], 0, 0, 0);
                sacc[rt][ct] = __builtin_amdgcn_mfma_f32_16x16x32_bf16(kb, qf[rt][1], sacc[rt][ct], 0, 0, 0);
            }
        }

        // P = exp(s/8): lane's 4 acc regs = 4 consecutive keys -> packed b64
        #pragma unroll
        for (int rt = 0; rt < 2; ++rt)
            #pragma unroll
            for (int ct = 0; ct < 8; ++ct) {
                short4v pk;
                #pragma unroll
                for (int r = 0; r < 4; ++r) {
                    float p = exp2f(sacc[rt][ct][r] * SC);
                    lsum[rt] += p;
                    pk[r] = f2bf(p);
                }
                *(short4v*)&myP[(rt*16 + l)*136 + ct*16 + qd*4] = pk;
            }

        // O += P V  (A = P rows from own strip, B = V^T frags direct global)
        #pragma unroll
        for (int kf = 0; kf < 4; ++kf) {
            short8 pa0 = *(const short8*)&myP[( 0 + l)*136 + kf*32 + qd*8];
            short8 pa1 = *(const short8*)&myP[(16 + l)*136 + kf*32 + qd*8];
            #pragma unroll
            for (int ht = 0; ht < 4; ++ht) {
                short8 vv = *(const short8*)(vbase + (size_t)(ht*16 + l)*2048 + kt*128 + kf*32 + qd*8);
                oacc[0][ht] = __builtin_amdgcn_mfma_f32_16x16x32_bf16(pa0, vv, oacc[0][ht], 0, 0, 0);
                oacc[1][ht] = __builtin_amdgcn_mfma_f32_16x16x32_bf16(pa1, vv, oacc[1][ht], 0, 0, 0);
            }
        }
    }

    // complete row sums (partials live across the 4 qd-groups at same l)
    #pragma unroll
    for (int rt = 0; rt < 2; ++rt) {
        lsum[rt] += __shfl_xor(lsum[rt], 16);
        lsum[rt] += __shfl_xor(lsum[rt], 32);
    }
    float inv[2][4];
    #pragma unroll
    for (int rt = 0; rt < 2; ++rt)
        #pragma unroll
        for (int r = 0; r < 4; ++r)
            inv[rt][r] = 1.0f / __shfl(lsum[rt], qd*4 + r);

    const int bb = bh >> 4, h = bh & 15;
    #pragma unroll
    for (int rt = 0; rt < 2; ++rt)
        #pragma unroll
        for (int ht = 0; ht < 4; ++ht)
            #pragma unroll
            for (int r = 0; r < 4; ++r) {
                const int s = q0 + w*32 + rt*16 + qd*4 + r;
                og[((size_t)bb*2048 + s)*1024 + h*64 + ht*16 + l] =
                    f2bf(oacc[rt][ht][r] * inv[rt][r]);
            }
}

// ---------------------------------------------------------------------------
extern "C" void kernel_launch(void* const* d_in, const int* in_sizes, int n_in,
                              void* d_out, int out_size, void* d_ws, size_t ws_size,
                              hipStream_t stream)
{
    const float* x  = (const float*)d_in[0];
    const float* fr = (const float*)d_in[1];
    const float* Wq = (const float*)d_in[2];
    const float* bq = (const float*)d_in[3];
    const float* Wk = (const float*)d_in[4];
    const float* bk = (const float*)d_in[5];
    const float* Wv = (const float*)d_in[6];
    const float* bv = (const float*)d_in[7];
    const float* Wo = (const float*)d_in[8];
    const float* bo = (const float*)d_in[9];
    float* out = (float*)d_out;

    short* ws    = (short*)d_ws;
    short* xb    = ws;                  // 4,194,304
    short* Wqkvb = xb    + 4194304;     // 3,145,728
    short* Wob   = Wqkvb + 3145728;     // 1,048,576
    short* qg    = Wob   + 1048576;     // [BH,S,HD]
    short* kg    = qg    + 4194304;     // [BH,S,HD]
    short* vtg   = kg    + 4194304;     // [BH,HD,S]
    short* og    = vtg   + 4194304;     // [B,S,H*HD]

    cast_all_kernel<<<8192, 256, 0, stream>>>(x, Wq, Wk, Wv, Wo, xb, Wqkvb, Wob);
    gemm_tile<1,128,64><<<dim3(48, 32), 256, 0, stream>>>(xb, Wqkvb, bq, bk, bv, fr, qg, kg, vtg);
    attn_mfma<<<dim3(16, 32), 256, 0, stream>>>(qg, kg, vtg, og);
    gemm_tile<0,64,64><<<dim3(16, 64), 256, 0, stream>>>(og, Wob, bo, nullptr, nullptr, nullptr,
                                                         out, nullptr, nullptr);
}

// Round 9
// 248.745 us; speedup vs baseline: 1.3106x; 1.3106x over previous
//
#include <hip/hip_runtime.h>
#include <cmath>

#define B_ 2
#define S_ 2048
#define D_ 1024
#define H_ 16
#define HD_ 64
#define M_ 4096   // B*S

typedef __attribute__((ext_vector_type(8))) short short8;
typedef __attribute__((ext_vector_type(4))) short short4v;
typedef __attribute__((ext_vector_type(4))) float f32x4;

// round-to-nearest-even f32 -> bf16 (values finite here)
__device__ __forceinline__ short f2bf(float x) {
    unsigned u = __builtin_bit_cast(unsigned, x);
    u += 0x7fffu + ((u >> 16) & 1u);
    return (short)(u >> 16);
}

__device__ __forceinline__ void gload_lds16(const short* g, short* l) {
    __builtin_amdgcn_global_load_lds(
        (const __attribute__((address_space(1))) unsigned int*)g,
        (__attribute__((address_space(3))) unsigned int*)l, 16, 0, 0);
}

// ---------------------------------------------------------------------------
// cast fp32 inputs to bf16
__global__ __launch_bounds__(256) void cast_all_kernel(
    const float* __restrict__ x,  const float* __restrict__ Wq,
    const float* __restrict__ Wk, const float* __restrict__ Wv,
    const float* __restrict__ Wo,
    short* __restrict__ xb, short* __restrict__ Wqkvb, short* __restrict__ Wob)
{
    const size_t i = (size_t)blockIdx.x * 256 + threadIdx.x;  // float4 index
    const float* src; short* dst; size_t off;
    if (i < 1048576)      { src = x;  dst = xb;              off = i; }
    else if (i < 1310720) { src = Wq; dst = Wqkvb;           off = i - 1048576; }
    else if (i < 1572864) { src = Wk; dst = Wqkvb + 1048576; off = i - 1310720; }
    else if (i < 1835008) { src = Wv; dst = Wqkvb + 2097152; off = i - 1572864; }
    else                  { src = Wo; dst = Wob;             off = i - 1835008; }
    float4 v = ((const float4*)src)[off];
    short4v o = { f2bf(v.x), f2bf(v.y), f2bf(v.z), f2bf(v.w) };
    ((short4v*)dst)[off] = o;
}

// ---------------------------------------------------------------------------
// Chunked-K MFMA GEMM: C = A @ W^T (+bias). Tile TM x TN, K-chunk = 128
// staged as 4 x BK32 sub-tiles in ONE burst (all global_load_lds in flight
// together), ONE vmcnt drain + barrier per 128 K-elements, then 4 compute
// sub-steps from LDS. Amortizes the depth-1 barrier convoy 4x.
// 4 waves in 2x2; wave tile (TM/2)x(TN/2).
// 128x64: LDS 48 KB -> 3 blocks/CU; grid 1536. 64x64: 32 KB -> 5/CU cap.
// MODE 0: fp32 out [M,1024] + bias
// MODE 1: fused QKV epilogue (q,k: bias+RoPE -> [BH,S,HD]; v: bias -> [BH,HD,S])
template<int MODE, int TM, int TN>
__global__ __launch_bounds__(256) void gemm_chunk(
    const short* __restrict__ A, const short* __restrict__ Bw,
    const float* __restrict__ b0p, const float* __restrict__ b1p, const float* __restrict__ b2p,
    const float* __restrict__ freqs,
    void* __restrict__ out0, void* __restrict__ out1, void* __restrict__ out2)
{
    constexpr int RT = TM / 32, CT = TN / 32;   // per-wave mfma tiles
    __shared__ __align__(16) short As[4*TM*32];
    __shared__ __align__(16) short Bs[4*TN*32];
    const int t = threadIdx.x;
    const int w = t >> 6;
    const int lane = t & 63;
    const int qd = lane >> 4, l = lane & 15;
    const int n0 = blockIdx.x * TN, m0 = blockIdx.y * TM;
    const int wr = (w >> 1) * (TM/2), wc = (w & 1) * (TN/2);
    const int srow = lane >> 2;          // 16 rows per wave-call
    const int scol = (lane & 3) * 8;

    f32x4 acc[RT][CT] = {};

    for (int k0 = 0; k0 < 1024; k0 += 128) {
        __syncthreads();   // prev chunk done being read from LDS
        #pragma unroll
        for (int sub = 0; sub < 4; ++sub) {
            #pragma unroll
            for (int j = 0; j < TM/64; ++j) {
                const int rr = (j*4 + w) * 16;
                gload_lds16(A + (size_t)(m0 + rr + srow)*1024 + k0 + sub*32 + scol,
                            &As[sub*TM*32 + rr*32]);
            }
            #pragma unroll
            for (int j = 0; j < TN/64; ++j) {
                const int rr = (j*4 + w) * 16;
                gload_lds16(Bw + (size_t)(n0 + rr + srow)*1024 + k0 + sub*32 + scol,
                            &Bs[sub*TN*32 + rr*32]);
            }
        }
        __syncthreads();   // single drain for the whole 4-sub burst
        #pragma unroll
        for (int sub = 0; sub < 4; ++sub) {
            short8 af[RT], bf[CT];
            #pragma unroll
            for (int rt = 0; rt < RT; ++rt)
                af[rt] = *(const short8*)&As[sub*TM*32 + (wr + rt*16 + l)*32 + qd*8];
            #pragma unroll
            for (int ct = 0; ct < CT; ++ct)
                bf[ct] = *(const short8*)&Bs[sub*TN*32 + (wc + ct*16 + l)*32 + qd*8];
            #pragma unroll
            for (int rt = 0; rt < RT; ++rt)
                #pragma unroll
                for (int ct = 0; ct < CT; ++ct)
                    acc[rt][ct] = __builtin_amdgcn_mfma_f32_16x16x32_bf16(af[rt], bf[ct], acc[rt][ct], 0, 0, 0);
        }
    }

    if (MODE == 0) {
        float* out = (float*)out0;
        #pragma unroll
        for (int rt = 0; rt < RT; ++rt)
            #pragma unroll
            for (int ct = 0; ct < CT; ++ct) {
                const int n = n0 + wc + ct*16 + l;
                const float bias = b0p[n];
                #pragma unroll
                for (int r = 0; r < 4; ++r) {
                    const int m = m0 + wr + rt*16 + qd*4 + r;
                    out[(size_t)m*1024 + n] = acc[rt][ct][r] + bias;
                }
            }
    } else {
        const int sel = n0 >> 10;          // 0=q 1=k 2=v (uniform per block)
        const int nb = n0 & 1023;
        const float* bias = (sel == 0) ? b0p : (sel == 1) ? b1p : b2p;
        if (sel < 2) {
            short* outg = (short*)((sel == 0) ? out0 : out1);
            #pragma unroll
            for (int rt = 0; rt < RT; ++rt)
                #pragma unroll
                for (int ct = 0; ct < CT; ++ct) {
                    const int d = nb + wc + ct*16 + l;
                    const float bsv = bias[d];
                    const int h = d >> 6, hd = d & 63;
                    #pragma unroll
                    for (int r = 0; r < 4; ++r) {
                        const int m = m0 + wr + rt*16 + qd*4 + r;
                        const int bb = m >> 11, s = m & 2047;
                        float val = acc[rt][ct][r] + bsv;
                        float pv = __shfl_xor(val, 1);
                        const float* f = freqs + (size_t)s*128 + (size_t)(hd >> 1)*4;
                        float o = (d & 1) ? (f[2]*pv + f[3]*val) : (f[0]*val + f[1]*pv);
                        outg[((size_t)(bb*16 + h)*2048 + s)*64 + hd] = f2bf(o);
                    }
                }
        } else {
            short* outv = (short*)out2;
            #pragma unroll
            for (int rt = 0; rt < RT; ++rt)
                #pragma unroll
                for (int ct = 0; ct < CT; ++ct) {
                    const int d = nb + wc + ct*16 + l;
                    const float bsv = bias[d];
                    const int h = d >> 6, hd = d & 63;
                    const int m0r = m0 + wr + rt*16 + qd*4;
                    const int bb = m0r >> 11, s0 = m0r & 2047;
                    short4v pk;
                    #pragma unroll
                    for (int r = 0; r < 4; ++r) pk[r] = f2bf(acc[rt][ct][r] + bsv);
                    *(short4v*)&outv[((size_t)(bb*16 + h)*64 + hd)*2048 + s0] = pk;  // v^T
                }
        }
    }
}

// ---------------------------------------------------------------------------
// MFMA flash attention — R5 design (best measured). Block = 128 queries of
// one (b,h); 4 waves x 32 queries. S-phase computes S^T = mfma(K,Q): lane's
// 4 acc regs = 4 consecutive keys -> packed b64 P-writes. P reuses the K
// buffer; P rows are wave-local so the P write->read needs no barrier.
__global__ __launch_bounds__(256) void attn_mfma(
    const short* __restrict__ qg, const short* __restrict__ kg,
    const short* __restrict__ vtg, short* __restrict__ og)
{
    __shared__ __align__(16) short KP[128*136];
    __shared__ __align__(16) short Vt[64*136];

    const int t = threadIdx.x;
    const int w = t >> 6;
    const int lane = t & 63;
    const int qd = lane >> 4, l = lane & 15;
    const int q0 = blockIdx.x * 128;
    const int bh = blockIdx.y;

    short8 qf[2][2];
    const short* qb = qg + ((size_t)bh*2048 + q0 + w*32)*64;
    #pragma unroll
    for (int rt = 0; rt < 2; ++rt)
        #pragma unroll
        for (int kf = 0; kf < 2; ++kf)
            qf[rt][kf] = *(const short8*)&qb[(rt*16 + l)*64 + kf*32 + qd*8];

    f32x4 oacc[2][4] = {};
    float lsum[2] = {};

    const short* kbase = kg  + (size_t)bh*2048*64;
    const short* vbase = vtg + (size_t)bh*64*2048;
    const float SC = 0.125f * 1.44269504088896340736f;

    for (int kt = 0; kt < 16; ++kt) {
        __syncthreads();
        {   // stage K [128][64]
            const short* src = kbase + (size_t)(kt*128 + (t>>1))*64 + (t&1)*32;
            short* dst = &KP[(t>>1)*136 + (t&1)*32];
            *(short8*)(dst+0)  = *(const short8*)(src+0);
            *(short8*)(dst+8)  = *(const short8*)(src+8);
            *(short8*)(dst+16) = *(const short8*)(src+16);
            *(short8*)(dst+24) = *(const short8*)(src+24);
        }
        {   // stage V^T [64][128]
            const short* src = vbase + (size_t)(t>>2)*2048 + kt*128 + (t&3)*32;
            short* dst = &Vt[(t>>2)*136 + (t&3)*32];
            *(short8*)(dst+0)  = *(const short8*)(src+0);
            *(short8*)(dst+8)  = *(const short8*)(src+8);
            *(short8*)(dst+16) = *(const short8*)(src+16);
            *(short8*)(dst+24) = *(const short8*)(src+24);
        }
        __syncthreads();

        f32x4 sacc[2][8] = {};
        #pragma unroll
        for (int ct = 0; ct < 8; ++ct) {
            short8 k0f = *(const short8*)&KP[(ct*16 + l)*136 + qd*8];
            short8 k1f = *(const short8*)&KP[(ct*16 + l)*136 + 32 + qd*8];
            #pragma unroll
            for (int rt = 0; rt < 2; ++rt) {
                sacc[rt][ct] = __builtin_amdgcn_mfma_f32_16x16x32_bf16(k0f, qf[rt][0], sacc[rt][ct], 0, 0, 0);
                sacc[rt][ct] = __builtin_amdgcn_mfma_f32_16x16x32_bf16(k1f, qf[rt][1], sacc[rt][ct], 0, 0, 0);
            }
        }
        __syncthreads();   // all waves done reading K before P overwrites

        #pragma unroll
        for (int rt = 0; rt < 2; ++rt)
            #pragma unroll
            for (int ct = 0; ct < 8; ++ct) {
                short4v pk;
                #pragma unroll
                for (int r = 0; r < 4; ++r) {
                    float p = exp2f(sacc[rt][ct][r] * SC);
                    lsum[rt] += p;
                    pk[r] = f2bf(p);
                }
                *(short4v*)&KP[(w*32 + rt*16 + l)*136 + ct*16 + qd*4] = pk;
            }

        #pragma unroll
        for (int kf = 0; kf < 4; ++kf) {
            short8 pa0 = *(const short8*)&KP[(w*32 +  0 + l)*136 + kf*32 + qd*8];
            short8 pa1 = *(const short8*)&KP[(w*32 + 16 + l)*136 + kf*32 + qd*8];
            #pragma unroll
            for (int ht = 0; ht < 4; ++ht) {
                short8 vb = *(const short8*)&Vt[(ht*16 + l)*136 + kf*32 + qd*8];
                oacc[0][ht] = __builtin_amdgcn_mfma_f32_16x16x32_bf16(pa0, vb, oacc[0][ht], 0, 0, 0);
                oacc[1][ht] = __builtin_amdgcn_mfma_f32_16x16x32_bf16(pa1, vb, oacc[1][ht], 0, 0, 0);
            }
        }
    }

    #pragma unroll
    for (int rt = 0; rt < 2; ++rt) {
        lsum[rt] += __shfl_xor(lsum[rt], 16);
        lsum[rt] += __shfl_xor(lsum[rt], 32);
    }
    float inv[2][4];
    #pragma unroll
    for (int rt = 0; rt < 2; ++rt)
        #pragma unroll
        for (int r = 0; r < 4; ++r)
            inv[rt][r] = 1.0f / __shfl(lsum[rt], qd*4 + r);

    const int bb = bh >> 4, h = bh & 15;
    #pragma unroll
    for (int rt = 0; rt < 2; ++rt)
        #pragma unroll
        for (int ht = 0; ht < 4; ++ht)
            #pragma unroll
            for (int r = 0; r < 4; ++r) {
                const int s = q0 + w*32 + rt*16 + qd*4 + r;
                og[((size_t)bb*2048 + s)*1024 + h*64 + ht*16 + l] =
                    f2bf(oacc[rt][ht][r] * inv[rt][r]);
            }
}

// ---------------------------------------------------------------------------
extern "C" void kernel_launch(void* const* d_in, const int* in_sizes, int n_in,
                              void* d_out, int out_size, void* d_ws, size_t ws_size,
                              hipStream_t stream)
{
    const float* x  = (const float*)d_in[0];
    const float* fr = (const float*)d_in[1];
    const float* Wq = (const float*)d_in[2];
    const float* bq = (const float*)d_in[3];
    const float* Wk = (const float*)d_in[4];
    const float* bk = (const float*)d_in[5];
    const float* Wv = (const float*)d_in[6];
    const float* bv = (const float*)d_in[7];
    const float* Wo = (const float*)d_in[8];
    const float* bo = (const float*)d_in[9];
    float* out = (float*)d_out;

    short* ws    = (short*)d_ws;
    short* xb    = ws;                  // 4,194,304
    short* Wqkvb = xb    + 4194304;     // 3,145,728
    short* Wob   = Wqkvb + 3145728;     // 1,048,576
    short* qg    = Wob   + 1048576;     // [BH,S,HD]
    short* kg    = qg    + 4194304;     // [BH,S,HD]
    short* vtg   = kg    + 4194304;     // [BH,HD,S]
    short* og    = vtg   + 4194304;     // [B,S,H*HD]

    cast_all_kernel<<<8192, 256, 0, stream>>>(x, Wq, Wk, Wv, Wo, xb, Wqkvb, Wob);
    gemm_chunk<1,128,64><<<dim3(48, 32), 256, 0, stream>>>(xb, Wqkvb, bq, bk, bv, fr, qg, kg, vtg);
    attn_mfma<<<dim3(16, 32), 256, 0, stream>>>(qg, kg, vtg, og);
    gemm_chunk<0,64,64><<<dim3(16, 64), 256, 0, stream>>>(og, Wob, bo, nullptr, nullptr, nullptr,
                                                          out, nullptr, nullptr);
}